// Round 1
// baseline (1911.926 us; speedup 1.0000x reference)
//
#include <hip/hip_runtime.h>

#define NUM_USERS 100000
#define NUM_ITEMS 100000
#define NN        200000          // N = NUM_USERS + NUM_ITEMS
#define DD        64
#define EE        3200000

// ---------------------------------------------------------------------------
// Edge scatter: one wave (64 lanes) per edge, lane d handles feature dim d.
//   agg[dst][d] += w * x[src][d]
// Gather source is split into two base pointers (user part / item part) so the
// same kernel serves layer 1 (two separate embedding arrays) and layer 2
// (one contiguous h1 array, passed as xu=h1, xi=h1+NUM_USERS*64).
// ---------------------------------------------------------------------------
__global__ __launch_bounds__(256) void edge_scatter(
    const int*   __restrict__ ei,   // [2*E] src then dst
    const float* __restrict__ ew,   // [E]
    const float* __restrict__ xu,   // rows 0..NUM_USERS
    const float* __restrict__ xi,   // rows NUM_USERS..N (base already offset)
    float*       __restrict__ agg)  // [N,64] accumulate
{
    const int e = blockIdx.x * 4 + (threadIdx.x >> 6);
    const int d = threadIdx.x & 63;
    if (e >= EE) return;

    const int   src = ei[e];
    const int   dst = ei[EE + e];
    const float w   = ew[e];

    const float* xs = (src < NUM_USERS)
                        ? (xu + (size_t)src * DD)
                        : (xi + (size_t)(src - NUM_USERS) * DD);

    const float v = w * xs[d];
#if defined(__HIP_DEVICE_COMPILE__)
    unsafeAtomicAdd(agg + (size_t)dst * DD + d, v);   // hw global_atomic_add_f32
#else
    atomicAdd(agg + (size_t)dst * DD + d, v);
#endif
}

// ---------------------------------------------------------------------------
// Fused residual-average + linear:  out[n] = (agg[n] * 0.5) @ W + b
// (agg was pre-initialized to x, so agg = x + sum(msgs) and updated = agg*0.5)
// One wave per row; W staged in LDS; row values broadcast via __shfl.
// ---------------------------------------------------------------------------
__global__ __launch_bounds__(256) void row_linear(
    const float* __restrict__ agg,  // [N,64]
    const float* __restrict__ W,    // [64,64] row-major (k, j)
    const float* __restrict__ b,    // [64]
    float*       __restrict__ out)  // [N,64]
{
    __shared__ float Ws[DD * DD];
    const int t = threadIdx.x;
    // 4096 floats / 256 threads = 16 each, as float4
    for (int i = t; i < (DD * DD / 4); i += 256)
        ((float4*)Ws)[i] = ((const float4*)W)[i];
    __syncthreads();

    const int row  = blockIdx.x * 4 + (t >> 6);
    const int lane = t & 63;
    if (row >= NN) return;

    const float u   = agg[(size_t)row * DD + lane] * 0.5f;
    float       acc = b[lane];
#pragma unroll
    for (int k = 0; k < DD; ++k) {
        const float uk = __shfl(u, k, 64);
        acc = fmaf(uk, Ws[k * DD + lane], acc);
    }
    out[(size_t)row * DD + lane] = acc;
}

extern "C" void kernel_launch(void* const* d_in, const int* in_sizes, int n_in,
                              void* d_out, int out_size, void* d_ws, size_t ws_size,
                              hipStream_t stream) {
    const int*   edge_index = (const int*)  d_in[0];  // [2*E]
    const float* edge_weight= (const float*)d_in[1];  // [E]
    const float* user_emb   = (const float*)d_in[2];  // [100000,64]
    const float* item_emb   = (const float*)d_in[3];  // [100000,64]
    const float* W1         = (const float*)d_in[4];
    const float* b1         = (const float*)d_in[5];
    const float* W2         = (const float*)d_in[6];
    const float* b2         = (const float*)d_in[7];
    float*       out        = (float*)d_out;          // [N,64]

    float* agg = (float*)d_ws;                        // N*64 floats = 51.2 MB

    const size_t half_bytes = (size_t)NUM_USERS * DD * sizeof(float);
    const size_t full_bytes = (size_t)NN * DD * sizeof(float);

    const int edge_blocks = (EE + 3) / 4;             // 4 edges per 256-thread block
    const int row_blocks  = (NN + 3) / 4;             // 4 rows  per 256-thread block

    // ---- Layer 1 ----
    // agg = x  (residual term; also provides the +x in (agg + x))
    hipMemcpyAsync(agg, user_emb, half_bytes, hipMemcpyDeviceToDevice, stream);
    hipMemcpyAsync((char*)agg + half_bytes, item_emb, half_bytes,
                   hipMemcpyDeviceToDevice, stream);
    edge_scatter<<<edge_blocks, 256, 0, stream>>>(edge_index, edge_weight,
                                                  user_emb, item_emb, agg);
    row_linear<<<row_blocks, 256, 0, stream>>>(agg, W1, b1, out);   // out = h1

    // ---- Layer 2 ----
    hipMemcpyAsync(agg, out, full_bytes, hipMemcpyDeviceToDevice, stream);
    edge_scatter<<<edge_blocks, 256, 0, stream>>>(edge_index, edge_weight,
                                                  out, out + (size_t)NUM_USERS * DD,
                                                  agg);
    row_linear<<<row_blocks, 256, 0, stream>>>(agg, W2, b2, out);
}

// Round 2
// 1032.507 us; speedup vs baseline: 1.8517x; 1.8517x over previous
//
#include <hip/hip_runtime.h>

#define NUM_USERS 100000
#define NN        200000          // N = users + items
#define DD        64
#define EE        3200000
#define SCAN_CHUNK 2048
#define NB_SCAN   ((NN + SCAN_CHUNK - 1) / SCAN_CHUNK)   // 98 blocks

// ---------------------------------------------------------------------------
// CSR build, step 1: histogram of dst degrees.
// ---------------------------------------------------------------------------
__global__ __launch_bounds__(256) void hist_kernel(
    const int* __restrict__ ei, int* __restrict__ counts)
{
    const int e = blockIdx.x * 256 + threadIdx.x;
    if (e < EE) atomicAdd(&counts[ei[EE + e]], 1);
}

// Step 2a: per-block partial sums of counts (2048 counts per block).
__global__ __launch_bounds__(256) void scan_partials_kernel(
    const int* __restrict__ counts, int* __restrict__ bsum)
{
    __shared__ int s[256];
    const int t = threadIdx.x;
    int sum = 0;
    for (int i = t; i < SCAN_CHUNK; i += 256) {
        const int idx = blockIdx.x * SCAN_CHUNK + i;
        sum += (idx < NN) ? counts[idx] : 0;
    }
    s[t] = sum; __syncthreads();
    for (int off = 128; off > 0; off >>= 1) {
        if (t < off) s[t] += s[t + off];
        __syncthreads();
    }
    if (t == 0) bsum[blockIdx.x] = s[0];
}

// Step 2b: exclusive scan of the 98 partials (single block).
__global__ __launch_bounds__(128) void scan_top_kernel(int* __restrict__ bsum)
{
    __shared__ int s[128];
    const int t = threadIdx.x;
    const int v = (t < NB_SCAN) ? bsum[t] : 0;
    s[t] = v; __syncthreads();
    for (int off = 1; off < 128; off <<= 1) {
        int add = (t >= off) ? s[t - off] : 0;
        __syncthreads();
        s[t] += add;
        __syncthreads();
    }
    if (t < NB_SCAN) bsum[t] = s[t] - v;   // exclusive
}

// Step 2c: write row_ptr (and a scratch copy `ofs` for the reorder pass).
__global__ __launch_bounds__(256) void scan_write_kernel(
    const int* __restrict__ counts, const int* __restrict__ bsum,
    int* __restrict__ row_ptr, int* __restrict__ ofs)
{
    __shared__ int s[256];
    const int t    = threadIdx.x;
    const int base = blockIdx.x * SCAN_CHUNK + t * 8;
    int c[8], ex[8], run = 0;
#pragma unroll
    for (int j = 0; j < 8; ++j) {
        const int idx = base + j;
        c[j] = (idx < NN) ? counts[idx] : 0;
        ex[j] = run; run += c[j];
    }
    s[t] = run; __syncthreads();
    for (int off = 1; off < 256; off <<= 1) {
        int add = (t >= off) ? s[t - off] : 0;
        __syncthreads();
        s[t] += add;
        __syncthreads();
    }
    const int thread_base = bsum[blockIdx.x] + s[t] - run;
#pragma unroll
    for (int j = 0; j < 8; ++j) {
        const int idx = base + j;
        if (idx < NN) {
            const int v = thread_base + ex[j];
            row_ptr[idx] = v;
            ofs[idx]     = v;
        }
    }
    if (blockIdx.x == 0 && t == 0) row_ptr[NN] = EE;
}

// Step 3: scatter edges into dst-sorted order. Order within a bucket is
// nondeterministic (atomic), which only permutes the fp add order — within
// tolerance.
__global__ __launch_bounds__(256) void reorder_kernel(
    const int* __restrict__ ei, const float* __restrict__ ew,
    int* __restrict__ ofs, int2* __restrict__ edges)
{
    const int e = blockIdx.x * 256 + threadIdx.x;
    if (e >= EE) return;
    const int   src = ei[e];
    const int   dst = ei[EE + e];
    const float w   = ew[e];
    const int pos = atomicAdd(&ofs[dst], 1);
    edges[pos] = make_int2(src, __float_as_int(w));
}

// ---------------------------------------------------------------------------
// Fused GCN layer: one wave per dst node.
//   acc[d] = x[node][d] + sum_{e in CSR row} w_e * x[src_e][d]   (registers)
//   u = acc * 0.5 ;  out[node] = u @ W + b   (W in LDS, shfl broadcast)
// No atomics, no agg round-trip through global.
// ---------------------------------------------------------------------------
__global__ __launch_bounds__(256) void gcn_layer_kernel(
    const int2* __restrict__ edges, const int* __restrict__ row_ptr,
    const float* __restrict__ xu,   // rows 0..NUM_USERS
    const float* __restrict__ xi,   // rows NUM_USERS..N (base pre-offset)
    const float* __restrict__ W, const float* __restrict__ b,
    float* __restrict__ out)
{
    __shared__ float Ws[DD * DD];
    const int t = threadIdx.x;
    for (int i = t; i < (DD * DD / 4); i += 256)
        ((float4*)Ws)[i] = ((const float4*)W)[i];
    __syncthreads();

    const int node = blockIdx.x * 4 + (t >> 6);   // grid covers exactly NN
    const int lane = t & 63;

    const float* xres = (node < NUM_USERS)
                          ? (xu + (size_t)node * DD)
                          : (xi + (size_t)(node - NUM_USERS) * DD);
    float acc = xres[lane];

    const int beg = row_ptr[node];
    const int end = row_ptr[node + 1];
    int e = beg;
    for (; e + 2 <= end; e += 2) {                // unroll-2: two gathers in flight
        const int2 p0 = edges[e];
        const int2 p1 = edges[e + 1];
        const float* s0 = (p0.x < NUM_USERS) ? (xu + (size_t)p0.x * DD)
                                             : (xi + (size_t)(p0.x - NUM_USERS) * DD);
        const float* s1 = (p1.x < NUM_USERS) ? (xu + (size_t)p1.x * DD)
                                             : (xi + (size_t)(p1.x - NUM_USERS) * DD);
        const float v0 = s0[lane];
        const float v1 = s1[lane];
        acc = fmaf(__int_as_float(p0.y), v0, acc);
        acc = fmaf(__int_as_float(p1.y), v1, acc);
    }
    if (e < end) {
        const int2 p = edges[e];
        const float* s0 = (p.x < NUM_USERS) ? (xu + (size_t)p.x * DD)
                                            : (xi + (size_t)(p.x - NUM_USERS) * DD);
        acc = fmaf(__int_as_float(p.y), s0[lane], acc);
    }

    const float u = acc * 0.5f;
    float r = b[lane];
#pragma unroll
    for (int k = 0; k < DD; ++k)
        r = fmaf(__shfl(u, k, 64), Ws[k * DD + lane], r);

    out[(size_t)node * DD + lane] = r;
}

extern "C" void kernel_launch(void* const* d_in, const int* in_sizes, int n_in,
                              void* d_out, int out_size, void* d_ws, size_t ws_size,
                              hipStream_t stream) {
    const int*   edge_index  = (const int*)  d_in[0];  // [2*E] (int32 on device)
    const float* edge_weight = (const float*)d_in[1];
    const float* user_emb    = (const float*)d_in[2];
    const float* item_emb    = (const float*)d_in[3];
    const float* W1          = (const float*)d_in[4];
    const float* b1          = (const float*)d_in[5];
    const float* W2          = (const float*)d_in[6];
    const float* b2          = (const float*)d_in[7];
    float*       out         = (float*)d_out;

    // Workspace layout (all 64 B aligned):
    char* ws = (char*)d_ws;
    float* h1      = (float*)(ws);                          // N*64 f32 = 51,200,000 B
    int2*  edges   = (int2*) (ws + 51200000);               // E*8     = 25,600,000 B
    int*   row_ptr = (int*)  (ws + 76800000);               // (N+1)*4 ≈    800,064 B
    int*   ofs     = (int*)  (ws + 77600064);               // N*4     =    800,000 B
    int*   counts  = (int*)  (ws + 78400064);               // N*4     =    800,000 B
    int*   bsum    = (int*)  (ws + 79200064);               // 128*4

    const int edge_blocks = (EE + 255) / 256;               // 12500
    const int node_blocks = NN / 4;                         // 50000 (exact)

    // ---- CSR build (shared by both layers) ----
    hipMemsetAsync(counts, 0, NN * sizeof(int), stream);
    hist_kernel         <<<edge_blocks, 256, 0, stream>>>(edge_index, counts);
    scan_partials_kernel<<<NB_SCAN,     256, 0, stream>>>(counts, bsum);
    scan_top_kernel     <<<1,           128, 0, stream>>>(bsum);
    scan_write_kernel   <<<NB_SCAN,     256, 0, stream>>>(counts, bsum, row_ptr, ofs);
    reorder_kernel      <<<edge_blocks, 256, 0, stream>>>(edge_index, edge_weight,
                                                          ofs, edges);

    // ---- Layer 1: sources are the two embedding tables, output h1 ----
    gcn_layer_kernel<<<node_blocks, 256, 0, stream>>>(
        edges, row_ptr, user_emb, item_emb, W1, b1, h1);

    // ---- Layer 2: sources are h1, output d_out ----
    gcn_layer_kernel<<<node_blocks, 256, 0, stream>>>(
        edges, row_ptr, h1, h1 + (size_t)NUM_USERS * DD, W2, b2, out);
}

// Round 3
// 714.768 us; speedup vs baseline: 2.6749x; 1.4445x over previous
//
#include <hip/hip_runtime.h>
#include <hip/hip_fp16.h>

#define NUM_USERS 100000
#define NN        200000          // N = users + items
#define DD        64
#define EE        3200000
#define SCAN_CHUNK 2048
#define NB_SCAN   ((NN + SCAN_CHUNK - 1) / SCAN_CHUNK)   // 98 blocks

typedef _Float16 half8 __attribute__((ext_vector_type(8)));
typedef _Float16 half4 __attribute__((ext_vector_type(4)));
typedef float    f32x4 __attribute__((ext_vector_type(4)));

// ---------------------------------------------------------------------------
// CSR build (unchanged from round 2)
// ---------------------------------------------------------------------------
__global__ __launch_bounds__(256) void hist_kernel(
    const int* __restrict__ ei, int* __restrict__ counts)
{
    const int e = blockIdx.x * 256 + threadIdx.x;
    if (e < EE) atomicAdd(&counts[ei[EE + e]], 1);
}

__global__ __launch_bounds__(256) void scan_partials_kernel(
    const int* __restrict__ counts, int* __restrict__ bsum)
{
    __shared__ int s[256];
    const int t = threadIdx.x;
    int sum = 0;
    for (int i = t; i < SCAN_CHUNK; i += 256) {
        const int idx = blockIdx.x * SCAN_CHUNK + i;
        sum += (idx < NN) ? counts[idx] : 0;
    }
    s[t] = sum; __syncthreads();
    for (int off = 128; off > 0; off >>= 1) {
        if (t < off) s[t] += s[t + off];
        __syncthreads();
    }
    if (t == 0) bsum[blockIdx.x] = s[0];
}

__global__ __launch_bounds__(128) void scan_top_kernel(int* __restrict__ bsum)
{
    __shared__ int s[128];
    const int t = threadIdx.x;
    const int v = (t < NB_SCAN) ? bsum[t] : 0;
    s[t] = v; __syncthreads();
    for (int off = 1; off < 128; off <<= 1) {
        int add = (t >= off) ? s[t - off] : 0;
        __syncthreads();
        s[t] += add;
        __syncthreads();
    }
    if (t < NB_SCAN) bsum[t] = s[t] - v;   // exclusive
}

__global__ __launch_bounds__(256) void scan_write_kernel(
    const int* __restrict__ counts, const int* __restrict__ bsum,
    int* __restrict__ row_ptr, int* __restrict__ ofs)
{
    __shared__ int s[256];
    const int t    = threadIdx.x;
    const int base = blockIdx.x * SCAN_CHUNK + t * 8;
    int c[8], ex[8], run = 0;
#pragma unroll
    for (int j = 0; j < 8; ++j) {
        const int idx = base + j;
        c[j] = (idx < NN) ? counts[idx] : 0;
        ex[j] = run; run += c[j];
    }
    s[t] = run; __syncthreads();
    for (int off = 1; off < 256; off <<= 1) {
        int add = (t >= off) ? s[t - off] : 0;
        __syncthreads();
        s[t] += add;
        __syncthreads();
    }
    const int thread_base = bsum[blockIdx.x] + s[t] - run;
#pragma unroll
    for (int j = 0; j < 8; ++j) {
        const int idx = base + j;
        if (idx < NN) {
            const int v = thread_base + ex[j];
            row_ptr[idx] = v;
            ofs[idx]     = v;
        }
    }
    if (blockIdx.x == 0 && t == 0) row_ptr[NN] = EE;
}

__global__ __launch_bounds__(256) void reorder_kernel(
    const int* __restrict__ ei, const float* __restrict__ ew,
    int* __restrict__ ofs, int2* __restrict__ edges)
{
    const int e = blockIdx.x * 256 + threadIdx.x;
    if (e >= EE) return;
    const int   src = ei[e];
    const int   dst = ei[EE + e];
    const float w   = ew[e];
    const int pos = atomicAdd(&ofs[dst], 1);
    edges[pos] = make_int2(src, __float_as_int(w));
}

// ---------------------------------------------------------------------------
// fp32 embeddings -> fp16 gather table xh [N][64]
// ---------------------------------------------------------------------------
__global__ __launch_bounds__(256) void convert_x_kernel(
    const float* __restrict__ xu, const float* __restrict__ xi,
    _Float16* __restrict__ xh)
{
    const int i = blockIdx.x * 256 + threadIdx.x;      // one float4 each
    if (i >= NN * DD / 4) return;
    const float4 v = (i < NUM_USERS * DD / 4)
                       ? ((const float4*)xu)[i]
                       : ((const float4*)xi)[i - NUM_USERS * DD / 4];
    half4 o; o[0] = (_Float16)v.x; o[1] = (_Float16)v.y;
             o[2] = (_Float16)v.z; o[3] = (_Float16)v.w;
    ((half4*)xh)[i] = o;
}

// W [k][n] fp32 -> Wt [n][k] fp16 (B-fragment loads become contiguous 16 B)
__global__ __launch_bounds__(256) void convert_w_kernel(
    const float* __restrict__ W1, const float* __restrict__ W2,
    _Float16* __restrict__ Wt)
{
    const int idx = blockIdx.x * 256 + threadIdx.x;    // 2*4096
    if (idx >= 2 * DD * DD) return;
    const int mat = idx >> 12, rem = idx & 4095, k = rem >> 6, n = rem & 63;
    const float* W = mat ? W2 : W1;
    Wt[mat * DD * DD + n * DD + k] = (_Float16)W[k * DD + n];
}

// ---------------------------------------------------------------------------
// Aggregation: one wave per node, lane d = dim d. DS-free.
//   u[node] = 0.5 * ( xh[node] + sum_e w_e * xh[src_e] )   (fp32 acc, fp16 out)
// ---------------------------------------------------------------------------
__global__ __launch_bounds__(256) void aggregate_kernel(
    const int2* __restrict__ edges, const int* __restrict__ row_ptr,
    const _Float16* __restrict__ xh, _Float16* __restrict__ u)
{
    const int node = blockIdx.x * 4 + (threadIdx.x >> 6);   // grid covers NN exactly
    const int lane = threadIdx.x & 63;

    float acc = (float)xh[(size_t)node * DD + lane];        // residual term
    const int beg = row_ptr[node];
    const int end = row_ptr[node + 1];
    int e = beg;
    for (; e + 4 <= end; e += 4) {                          // 4 gathers in flight
        const int2 p0 = edges[e + 0];
        const int2 p1 = edges[e + 1];
        const int2 p2 = edges[e + 2];
        const int2 p3 = edges[e + 3];
        const float v0 = (float)xh[(size_t)p0.x * DD + lane];
        const float v1 = (float)xh[(size_t)p1.x * DD + lane];
        const float v2 = (float)xh[(size_t)p2.x * DD + lane];
        const float v3 = (float)xh[(size_t)p3.x * DD + lane];
        acc = fmaf(__int_as_float(p0.y), v0, acc);
        acc = fmaf(__int_as_float(p1.y), v1, acc);
        acc = fmaf(__int_as_float(p2.y), v2, acc);
        acc = fmaf(__int_as_float(p3.y), v3, acc);
    }
    for (; e < end; ++e) {
        const int2 p = edges[e];
        acc = fmaf(__int_as_float(p.y), (float)xh[(size_t)p.x * DD + lane], acc);
    }
    u[(size_t)node * DD + lane] = (_Float16)(acc * 0.5f);
}

// ---------------------------------------------------------------------------
// GEMM: out[N,64] = u[N,64] @ W[64,64] + b, via mfma_f32_16x16x32_f16.
// One wave per 16-row tile; W entirely in registers (8 frags from Wt[n][k]).
// A-frag: lane holds A[m=lane&15][k=quad*8+j]; C/D: col=lane&15, row=quad*4+r.
// ---------------------------------------------------------------------------
template<bool HALF_OUT>
__global__ __launch_bounds__(256) void gemm64_kernel(
    const _Float16* __restrict__ u, const _Float16* __restrict__ Wt,
    const float* __restrict__ bias, void* __restrict__ outp)
{
    const int wid  = blockIdx.x * 4 + (threadIdx.x >> 6);   // 0..12499
    const int lane = threadIdx.x & 63;
    const int m    = lane & 15;
    const int quad = lane >> 4;
    const size_t rowbase = (size_t)wid * 16;

    half8 bf[4][2];                                         // [col tile][k half]
#pragma unroll
    for (int c = 0; c < 4; ++c)
#pragma unroll
        for (int h = 0; h < 2; ++h)
            bf[c][h] = *(const half8*)(Wt + (size_t)(c * 16 + m) * DD + h * 32 + quad * 8);

    const half8 a0 = *(const half8*)(u + (rowbase + m) * DD +  0 + quad * 8);
    const half8 a1 = *(const half8*)(u + (rowbase + m) * DD + 32 + quad * 8);

    f32x4 acc[4];
#pragma unroll
    for (int c = 0; c < 4; ++c) {
        f32x4 z = {0.f, 0.f, 0.f, 0.f};
        z = __builtin_amdgcn_mfma_f32_16x16x32_f16(a0, bf[c][0], z, 0, 0, 0);
        z = __builtin_amdgcn_mfma_f32_16x16x32_f16(a1, bf[c][1], z, 0, 0, 0);
        acc[c] = z;
    }

#pragma unroll
    for (int c = 0; c < 4; ++c) {
        const float bv = bias[c * 16 + m];
#pragma unroll
        for (int r = 0; r < 4; ++r) {
            const size_t row = rowbase + quad * 4 + r;
            const float val = acc[c][r] + bv;
            if (HALF_OUT) ((_Float16*)outp)[row * DD + c * 16 + m] = (_Float16)val;
            else          ((float*)    outp)[row * DD + c * 16 + m] = val;
        }
    }
}

extern "C" void kernel_launch(void* const* d_in, const int* in_sizes, int n_in,
                              void* d_out, int out_size, void* d_ws, size_t ws_size,
                              hipStream_t stream) {
    const int*   edge_index  = (const int*)  d_in[0];
    const float* edge_weight = (const float*)d_in[1];
    const float* user_emb    = (const float*)d_in[2];
    const float* item_emb    = (const float*)d_in[3];
    const float* W1          = (const float*)d_in[4];
    const float* b1          = (const float*)d_in[5];
    const float* W2          = (const float*)d_in[6];
    const float* b2          = (const float*)d_in[7];
    float*       out         = (float*)d_out;

    // Workspace layout:
    char* ws = (char*)d_ws;
    _Float16* xh      = (_Float16*)(ws);                 // 25,600,000 B — xh, then h1 (fp16) aliases it
    _Float16* u       = (_Float16*)(ws + 25600000);      // 25,600,000 B
    int2*     edges   = (int2*)    (ws + 51200000);      // 25,600,000 B
    int*      row_ptr = (int*)     (ws + 76800000);      //    800,064 B
    int*      ofs     = (int*)     (ws + 77600064);      //    800,000 B
    int*      counts  = (int*)     (ws + 78400064);      //    800,000 B
    int*      bsum    = (int*)     (ws + 79200064);      //        512 B
    _Float16* Wt      = (_Float16*)(ws + 79200576);      //     16,384 B

    const int edge_blocks = (EE + 255) / 256;            // 12500
    const int node_blocks = NN / 4;                      // 50000
    const int gemm_blocks = (NN / 16) / 4;               // 3125

    // ---- CSR build ----
    hipMemsetAsync(counts, 0, NN * sizeof(int), stream);
    hist_kernel         <<<edge_blocks, 256, 0, stream>>>(edge_index, counts);
    scan_partials_kernel<<<NB_SCAN,     256, 0, stream>>>(counts, bsum);
    scan_top_kernel     <<<1,           128, 0, stream>>>(bsum);
    scan_write_kernel   <<<NB_SCAN,     256, 0, stream>>>(counts, bsum, row_ptr, ofs);
    reorder_kernel      <<<edge_blocks, 256, 0, stream>>>(edge_index, edge_weight,
                                                          ofs, edges);

    // ---- fp16 conversions ----
    convert_x_kernel<<<(NN * DD / 4 + 255) / 256, 256, 0, stream>>>(user_emb, item_emb, xh);
    convert_w_kernel<<<(2 * DD * DD + 255) / 256, 256, 0, stream>>>(W1, W2, Wt);

    // ---- Layer 1 ----
    aggregate_kernel<<<node_blocks, 256, 0, stream>>>(edges, row_ptr, xh, u);
    // h1 (fp16) overwrites xh — xh is no longer needed
    gemm64_kernel<true><<<gemm_blocks, 256, 0, stream>>>(u, Wt, b1, (void*)xh);

    // ---- Layer 2 ----
    aggregate_kernel<<<node_blocks, 256, 0, stream>>>(edges, row_ptr, xh, u);
    gemm64_kernel<false><<<gemm_blocks, 256, 0, stream>>>(u, Wt + DD * DD, b2, (void*)out);
}